// Round 1
// baseline (669.259 us; speedup 1.0000x reference)
//
#include <hip/hip_runtime.h>
#include <hip/hip_bf16.h>
#include <stdint.h>

typedef __bf16 bf16_t;
typedef bf16_t bf16x8 __attribute__((ext_vector_type(8)));
typedef bf16_t bf16x4 __attribute__((ext_vector_type(4)));
typedef float  f32x4  __attribute__((ext_vector_type(4)));

#define B_DIM 16384
#define N_DIM 4096

// async global->LDS, 16B per lane; LDS dest is wave-uniform base + lane*16
__device__ __forceinline__ void async_copy16(void* lptr, const void* gptr) {
  __builtin_amdgcn_global_load_lds(
      (const __attribute__((address_space(1))) unsigned int*)gptr,
      (__attribute__((address_space(3))) unsigned int*)lptr, 16, 0, 0);
}

// ---------------- cast w1/w2 fp32 -> bf16 ----------------
__global__ void cast_w_kernel(const float* __restrict__ w1, const float* __restrict__ w2,
                              bf16_t* __restrict__ w1b, bf16_t* __restrict__ w2b) {
  const float* src = blockIdx.y ? w2 : w1;
  bf16_t* dst = blockIdx.y ? w2b : w1b;
  size_t i = ((size_t)blockIdx.x * 256 + threadIdx.x) * 8;
  f32x4 a = *(const f32x4*)(src + i);
  f32x4 b = *(const f32x4*)(src + i + 4);
  bf16x8 o;
  o[0]=(bf16_t)a[0]; o[1]=(bf16_t)a[1]; o[2]=(bf16_t)a[2]; o[3]=(bf16_t)a[3];
  o[4]=(bf16_t)b[0]; o[5]=(bf16_t)b[1]; o[6]=(bf16_t)b[2]; o[7]=(bf16_t)b[3];
  *(bf16x8*)(dst + i) = o;
}

// ---------------- GEMM (128x128 tile, BK=64, 4 waves, 16x16x32 bf16 MFMA) ---
// MODE 0: GEMM1. A = x (fp32, converted during staging), B = w1b[zi].
//         Output scattered (through LDS) to inter[b*4096 + l*1024 + r] (bf16).
// MODE 1: GEMM2. A = inter (bf16), B = w2b[zi]. Output contiguous to
//         o2[b*4096 + zi*1024 + s] (bf16).
// MODE 2: GEMM2 direct (ws-poor fallback): fp32 strided store to out + bias.
// grid: x = qt (8 col-tiles), y = bt (128 b-tiles), z = zi (k or l)
template<int MODE>
__global__ __launch_bounds__(256)
void monarch_gemm(const float* __restrict__ Af, const bf16_t* __restrict__ Ab,
                  const bf16_t* __restrict__ Wb, bf16_t* __restrict__ Outb,
                  float* __restrict__ Outf, const float* __restrict__ bias)
{
  // stage: As [0..8191] (128 rows x 64), Bs [8192..16383]; epilogue: Cs[128][132]
  __shared__ bf16_t lds[128 * 132];
  const int tid  = threadIdx.x;
  const int lane = tid & 63;
  const int wid  = tid >> 6;
  const int wm   = wid >> 1;      // 2x2 wave grid, each wave 64x64
  const int wn   = wid & 1;
  const int qt = blockIdx.x, bt = blockIdx.y, zi = blockIdx.z;

  const long arow0 = (long)bt * 128;
  const long acol0 = (long)zi * 1024;       // col base inside the 4096-wide A row
  const bf16_t* Wblk = Wb + ((size_t)zi << 20);

  f32x4 acc[4][4] = {};

  // staging helpers
  const int sRow = tid >> 3;                 // MODE0 A-stage: 32 rows/pass
  const int sC8  = tid & 7;                  // 8-elem chunk within 64-wide row
  const int gRow = lane >> 3;                // gload_lds: row within 8-row chunk
  const int gChunk = (lane & 7) ^ gRow;      // pre-swizzled source 16B chunk

  for (int kt = 0; kt < 16; ++kt) {
    const int k0 = kt * 64;
    // ---- stage B (and A for MODE>=1) via global_load_lds, swizzled source --
    #pragma unroll
    for (int it = 0; it < 4; ++it) {
      const int R = (wid * 4 + it) * 8 + gRow;          // tile row 0..127
      const bf16_t* srcB = Wblk + ((size_t)(qt * 128 + R)) * 1024 + k0 + gChunk * 8;
      async_copy16((void*)&lds[8192 + (wid * 4 + it) * 512], srcB);
      if (MODE >= 1) {
        const bf16_t* srcA = Ab + (arow0 + R) * 4096 + acol0 + k0 + gChunk * 8;
        async_copy16((void*)&lds[(wid * 4 + it) * 512], srcA);
      }
    }
    if (MODE == 0) {
      // A: fp32 -> bf16 reg-staged with the same XOR-swizzle
      #pragma unroll
      for (int ps = 0; ps < 4; ++ps) {
        const int r = ps * 32 + sRow;
        const float* sa = Af + (arow0 + r) * 4096 + acol0 + k0 + sC8 * 8;
        f32x4 u = *(const f32x4*)sa;
        f32x4 v = *(const f32x4*)(sa + 4);
        bf16x8 pk;
        pk[0]=(bf16_t)u[0]; pk[1]=(bf16_t)u[1]; pk[2]=(bf16_t)u[2]; pk[3]=(bf16_t)u[3];
        pk[4]=(bf16_t)v[0]; pk[5]=(bf16_t)v[1]; pk[6]=(bf16_t)v[2]; pk[7]=(bf16_t)v[3];
        *(bf16x8*)&lds[r * 64 + ((sC8 ^ (r & 7)) * 8)] = pk;
      }
    }
    __syncthreads();
    // ---- compute: 2 x (8 ds_read_b128 + 16 MFMA) ----
    #pragma unroll
    for (int kk = 0; kk < 2; ++kk) {
      bf16x8 av[4], bv[4];
      const int kcol = kk * 32 + (lane >> 4) * 8;
      #pragma unroll
      for (int m = 0; m < 4; ++m) {
        const int r = wm * 64 + m * 16 + (lane & 15);
        av[m] = *(const bf16x8*)&lds[r * 64 + (kcol ^ ((r & 7) * 8))];
      }
      #pragma unroll
      for (int n = 0; n < 4; ++n) {
        const int r = wn * 64 + n * 16 + (lane & 15);
        bv[n] = *(const bf16x8*)&lds[8192 + r * 64 + (kcol ^ ((r & 7) * 8))];
      }
      #pragma unroll
      for (int m = 0; m < 4; ++m)
        #pragma unroll
        for (int n = 0; n < 4; ++n)
          acc[m][n] = __builtin_amdgcn_mfma_f32_16x16x32_bf16(av[m], bv[n], acc[m][n], 0, 0, 0);
    }
    __syncthreads();
  }

  // ---- epilogue: acc -> Cs[128][132] (padded, conflict-free writes) ----
  {
    const int rg = lane >> 4;
    const int cl = lane & 15;
    #pragma unroll
    for (int m = 0; m < 4; ++m)
      #pragma unroll
      for (int n = 0; n < 4; ++n) {
        const int row = wm * 64 + m * 16 + rg * 4;
        const int col = wn * 64 + n * 16 + cl;
        #pragma unroll
        for (int j = 0; j < 4; ++j)
          lds[(row + j) * 132 + col] = (bf16_t)acc[m][n][j];
      }
  }
  __syncthreads();

  if (MODE == 0) {
    // scatter P1: col q -> (l=q&3, r'=q>>2); store 16B runs of 8 consecutive r
    #pragma unroll
    for (int i = 0; i < 8; ++i) {
      const int s = i * 256 + tid;          // 2048 16B-segments
      const int row  = s >> 4;
      const int l    = (s >> 2) & 3;
      const int part = s & 3;
      bf16x8 v;
      #pragma unroll
      for (int u = 0; u < 8; ++u) v[u] = lds[row * 132 + l + 4 * (part * 8 + u)];
      const size_t b = arow0 + row;
      const int rg = zi * 256 + qt * 32 + part * 8;
      *(bf16x8*)&Outb[b * 4096 + l * 1024 + rg] = v;
    }
  } else if (MODE == 1) {
    // contiguous rows into o2[b*4096 + zi*1024 + s]
    #pragma unroll
    for (int i = 0; i < 8; ++i) {
      const int s = i * 256 + tid;
      const int row = s >> 4;
      const int ch  = s & 15;
      union { bf16x4 h[2]; bf16x8 v8; } u;
      u.h[0] = *(const bf16x4*)&lds[row * 132 + ch * 8];
      u.h[1] = *(const bf16x4*)&lds[row * 132 + ch * 8 + 4];
      *(bf16x8*)&Outb[(arow0 + row) * 4096 + (size_t)zi * 1024 + qt * 128 + ch * 8] = u.v8;
    }
  } else {
    // direct strided fp32 store + bias (fallback when ws too small for o2)
    for (int i = 0; i < 64; ++i) {
      const int e = i * 256 + tid;
      const int row = e >> 7, col = e & 127;
      const int sg = qt * 128 + col;
      const float val = (float)lds[row * 132 + col] + bias[sg * 4 + zi];
      Outf[(arow0 + row) * 4096 + (size_t)sg * 4 + zi] = val;
    }
  }
}

// ---------------- P2 + bias: out[b, s*4+l] = o2[b,l,s] + bias ----------------
__global__ void permute_bias_kernel(const bf16_t* __restrict__ o2,
                                    const float* __restrict__ bias,
                                    float* __restrict__ out) {
  const int t = blockIdx.x * 256 + threadIdx.x;
  const int b = t >> 8;
  const int s0 = (t & 255) * 4;
  const size_t rowb = (size_t)b * 4096;
  bf16x4 vl[4];
  #pragma unroll
  for (int l = 0; l < 4; ++l) vl[l] = *(const bf16x4*)(o2 + rowb + l * 1024 + s0);
  #pragma unroll
  for (int si = 0; si < 4; ++si) {
    f32x4 bb = *(const f32x4*)(bias + (size_t)(s0 + si) * 4);
    f32x4 o;
    o[0] = (float)vl[0][si] + bb[0];
    o[1] = (float)vl[1][si] + bb[1];
    o[2] = (float)vl[2][si] + bb[2];
    o[3] = (float)vl[3][si] + bb[3];
    *(f32x4*)(out + rowb + (size_t)(s0 + si) * 4) = o;
  }
}

extern "C" void kernel_launch(void* const* d_in, const int* in_sizes, int n_in,
                              void* d_out, int out_size, void* d_ws, size_t ws_size,
                              hipStream_t stream) {
  const float* x    = (const float*)d_in[0];
  const float* w1   = (const float*)d_in[1];
  const float* w2   = (const float*)d_in[2];
  const float* bias = (const float*)d_in[3];
  float* out = (float*)d_out;

  char* ws = (char*)d_ws;
  const size_t wBytes     = (size_t)8 << 20;            // per w array (bf16)
  const size_t interBytes = (size_t)B_DIM * 4096 * 2;   // 134 MB
  bf16_t* w1b   = (bf16_t*)(ws);
  bf16_t* w2b   = (bf16_t*)(ws + wBytes);
  bf16_t* inter = (bf16_t*)(ws + 2 * wBytes);
  bf16_t* o2    = (bf16_t*)(ws + 2 * wBytes + interBytes);
  const bool full = ws_size >= 2 * wBytes + 2 * interBytes;

  cast_w_kernel<<<dim3(2048, 2), 256, 0, stream>>>(w1, w2, w1b, w2b);

  dim3 grid(8, 128, 4);
  monarch_gemm<0><<<grid, 256, 0, stream>>>(x, nullptr, w1b, inter, nullptr, nullptr);
  if (full) {
    monarch_gemm<1><<<grid, 256, 0, stream>>>(nullptr, inter, w2b, o2, nullptr, nullptr);
    permute_bias_kernel<<<16384, 256, 0, stream>>>(o2, bias, out);
  } else {
    monarch_gemm<2><<<grid, 256, 0, stream>>>(nullptr, inter, w2b, nullptr, out, bias);
  }
}

// Round 2
// 640.764 us; speedup vs baseline: 1.0445x; 1.0445x over previous
//
#include <hip/hip_runtime.h>
#include <hip/hip_bf16.h>
#include <stdint.h>

typedef __bf16 bf16_t;
typedef bf16_t bf16x8 __attribute__((ext_vector_type(8)));
typedef bf16_t bf16x4 __attribute__((ext_vector_type(4)));
typedef float  f32x4  __attribute__((ext_vector_type(4)));

#define B_DIM 16384

// async global->LDS, 16B per lane; LDS dest is wave-uniform base + lane*16
__device__ __forceinline__ void async_copy16(void* lptr, const void* gptr) {
  __builtin_amdgcn_global_load_lds(
      (const __attribute__((address_space(1))) unsigned int*)gptr,
      (__attribute__((address_space(3))) unsigned int*)lptr, 16, 0, 0);
}

// ---------------- cast x + w1 + w2 fp32 -> bf16 (full path) ----------------
__global__ void cast_all_kernel(const float* __restrict__ x, const float* __restrict__ w1,
                                const float* __restrict__ w2, bf16_t* __restrict__ xb,
                                bf16_t* __restrict__ w1b, bf16_t* __restrict__ w2b) {
  size_t c = (size_t)blockIdx.x * 256 + threadIdx.x;  // 8-elem chunk id
  const float* s; bf16_t* d; size_t off;
  if (c < 8388608)      { s = x;  d = xb;  off = c; }            // 16384*4096/8
  else if (c < 8912896) { s = w1; d = w1b; off = c - 8388608; }  // 4*1024*1024/8
  else                  { s = w2; d = w2b; off = c - 8912896; }
  size_t i = off * 8;
  f32x4 a = *(const f32x4*)(s + i);
  f32x4 b = *(const f32x4*)(s + i + 4);
  bf16x8 o;
  o[0]=(bf16_t)a[0]; o[1]=(bf16_t)a[1]; o[2]=(bf16_t)a[2]; o[3]=(bf16_t)a[3];
  o[4]=(bf16_t)b[0]; o[5]=(bf16_t)b[1]; o[6]=(bf16_t)b[2]; o[7]=(bf16_t)b[3];
  *(bf16x8*)(d + i) = o;
}

// ---------------- cast w1/w2 only (fallback path) ----------------
__global__ void cast_w_kernel(const float* __restrict__ w1, const float* __restrict__ w2,
                              bf16_t* __restrict__ w1b, bf16_t* __restrict__ w2b) {
  const float* src = blockIdx.y ? w2 : w1;
  bf16_t* dst = blockIdx.y ? w2b : w1b;
  size_t i = ((size_t)blockIdx.x * 256 + threadIdx.x) * 8;
  f32x4 a = *(const f32x4*)(src + i);
  f32x4 b = *(const f32x4*)(src + i + 4);
  bf16x8 o;
  o[0]=(bf16_t)a[0]; o[1]=(bf16_t)a[1]; o[2]=(bf16_t)a[2]; o[3]=(bf16_t)a[3];
  o[4]=(bf16_t)b[0]; o[5]=(bf16_t)b[1]; o[6]=(bf16_t)b[2]; o[7]=(bf16_t)b[3];
  *(bf16x8*)(dst + i) = o;
}

// ---------------- GEMM (128x128 tile, BK=64, 4 waves, 16x16x32 bf16 MFMA) ---
// ABF16: A staged via global_load_lds (bf16 source) vs fp32 reg-staged.
// EPI 0: P1-scatter epilogue -> inter[b*4096 + l*1024 + r]   (GEMM1)
// EPI 1: contiguous epilogue -> o2[b*4096 + zi*1024 + s]     (GEMM2 full)
// EPI 2: direct fp32 strided store + bias to out             (GEMM2 fallback)
// logical block: qt = col-tile (8), bt = row-tile (128), zi = k or l (4)
template<bool ABF16, int EPI>
__global__ __launch_bounds__(256)
void monarch_gemm(const float* __restrict__ Af, const bf16_t* __restrict__ Ab,
                  const bf16_t* __restrict__ Wb, bf16_t* __restrict__ Outb,
                  float* __restrict__ Outf, const float* __restrict__ bias)
{
  // stage: As [0..8191] (128 rows x 64), Bs [8192..16383]; epilogue: Cs[128][132]
  __shared__ bf16_t lds[128 * 132];
  const int tid  = threadIdx.x;
  const int lane = tid & 63;
  const int wid  = tid >> 6;
  const int wm   = wid >> 1;      // 2x2 wave grid, each wave 64x64
  const int wn   = wid & 1;
  // XCD-chunked swizzle: 4096 blocks over 8 XCDs, 512 consecutive logicals/XCD
  const int pb = blockIdx.x;
  const int lb = (pb & 7) * 512 + (pb >> 3);
  const int qt = lb & 7, bt = (lb >> 3) & 127, zi = lb >> 10;

  const long arow0 = (long)bt * 128;
  const long acol0 = (long)zi * 1024;       // col base inside the 4096-wide A row
  const bf16_t* Wblk = Wb + ((size_t)zi << 20);

  f32x4 acc[4][4] = {};

  // staging helpers
  const int sRow = tid >> 3;                 // fp32 A-stage: 32 rows/pass
  const int sC8  = tid & 7;                  // 8-elem chunk within 64-wide row
  const int gRow = lane >> 3;                // gload_lds: row within 8-row chunk
  const int gChunk = (lane & 7) ^ gRow;      // pre-swizzled source 16B chunk

  for (int kt = 0; kt < 16; ++kt) {
    const int k0 = kt * 64;
    // ---- stage B (and A if bf16) via global_load_lds, swizzled source ----
    #pragma unroll
    for (int it = 0; it < 4; ++it) {
      const int R = (wid * 4 + it) * 8 + gRow;          // tile row 0..127
      const bf16_t* srcB = Wblk + ((size_t)(qt * 128 + R)) * 1024 + k0 + gChunk * 8;
      async_copy16((void*)&lds[8192 + (wid * 4 + it) * 512], srcB);
      if (ABF16) {
        const bf16_t* srcA = Ab + (arow0 + R) * 4096 + acol0 + k0 + gChunk * 8;
        async_copy16((void*)&lds[(wid * 4 + it) * 512], srcA);
      }
    }
    if (!ABF16) {
      // A: fp32 -> bf16 reg-staged with the same XOR-swizzle
      #pragma unroll
      for (int ps = 0; ps < 4; ++ps) {
        const int r = ps * 32 + sRow;
        const float* sa = Af + (arow0 + r) * 4096 + acol0 + k0 + sC8 * 8;
        f32x4 u = *(const f32x4*)sa;
        f32x4 v = *(const f32x4*)(sa + 4);
        bf16x8 pk;
        pk[0]=(bf16_t)u[0]; pk[1]=(bf16_t)u[1]; pk[2]=(bf16_t)u[2]; pk[3]=(bf16_t)u[3];
        pk[4]=(bf16_t)v[0]; pk[5]=(bf16_t)v[1]; pk[6]=(bf16_t)v[2]; pk[7]=(bf16_t)v[3];
        *(bf16x8*)&lds[r * 64 + ((sC8 ^ (r & 7)) * 8)] = pk;
      }
    }
    __syncthreads();
    // ---- compute: 2 x (8 ds_read_b128 + 16 MFMA) ----
    #pragma unroll
    for (int kk = 0; kk < 2; ++kk) {
      bf16x8 av[4], bv[4];
      const int kcol = kk * 32 + (lane >> 4) * 8;
      #pragma unroll
      for (int m = 0; m < 4; ++m) {
        const int r = wm * 64 + m * 16 + (lane & 15);
        av[m] = *(const bf16x8*)&lds[r * 64 + (kcol ^ ((r & 7) * 8))];
      }
      #pragma unroll
      for (int n = 0; n < 4; ++n) {
        const int r = wn * 64 + n * 16 + (lane & 15);
        bv[n] = *(const bf16x8*)&lds[8192 + r * 64 + (kcol ^ ((r & 7) * 8))];
      }
      #pragma unroll
      for (int m = 0; m < 4; ++m)
        #pragma unroll
        for (int n = 0; n < 4; ++n)
          acc[m][n] = __builtin_amdgcn_mfma_f32_16x16x32_bf16(av[m], bv[n], acc[m][n], 0, 0, 0);
    }
    __syncthreads();
  }

  // ---- epilogue: acc -> Cs[128][132] (padded, conflict-free writes) ----
  {
    const int rg = lane >> 4;
    const int cl = lane & 15;
    #pragma unroll
    for (int m = 0; m < 4; ++m)
      #pragma unroll
      for (int n = 0; n < 4; ++n) {
        const int row = wm * 64 + m * 16 + rg * 4;
        const int col = wn * 64 + n * 16 + cl;
        #pragma unroll
        for (int j = 0; j < 4; ++j)
          lds[(row + j) * 132 + col] = (bf16_t)acc[m][n][j];
      }
  }
  __syncthreads();

  if (EPI == 0) {
    // scatter P1: col q -> (l=q&3, r'=q>>2); store 16B runs of 8 consecutive r
    #pragma unroll
    for (int i = 0; i < 8; ++i) {
      const int s = i * 256 + tid;          // 2048 16B-segments
      const int row  = s >> 4;
      const int l    = (s >> 2) & 3;
      const int part = s & 3;
      bf16x8 v;
      #pragma unroll
      for (int u = 0; u < 8; ++u) v[u] = lds[row * 132 + l + 4 * (part * 8 + u)];
      const size_t b = arow0 + row;
      const int rg2 = zi * 256 + qt * 32 + part * 8;
      *(bf16x8*)&Outb[b * 4096 + l * 1024 + rg2] = v;
    }
  } else if (EPI == 1) {
    // contiguous rows into o2[b*4096 + zi*1024 + s]
    #pragma unroll
    for (int i = 0; i < 8; ++i) {
      const int s = i * 256 + tid;
      const int row = s >> 4;
      const int ch  = s & 15;
      union { bf16x4 h[2]; bf16x8 v8; } u;
      u.h[0] = *(const bf16x4*)&lds[row * 132 + ch * 8];
      u.h[1] = *(const bf16x4*)&lds[row * 132 + ch * 8 + 4];
      *(bf16x8*)&Outb[(arow0 + row) * 4096 + (size_t)zi * 1024 + qt * 128 + ch * 8] = u.v8;
    }
  } else {
    // direct strided fp32 store + bias (fallback when ws too small for o2)
    for (int i = 0; i < 64; ++i) {
      const int e = i * 256 + tid;
      const int row = e >> 7, col = e & 127;
      const int sg = qt * 128 + col;
      const float val = (float)lds[row * 132 + col] + bias[sg * 4 + zi];
      Outf[(arow0 + row) * 4096 + (size_t)sg * 4 + zi] = val;
    }
  }
}

// ---------------- P2 + bias: out[b, s*4+l] = o2[b,l,s] + bias ----------------
__global__ void permute_bias_kernel(const bf16_t* __restrict__ o2,
                                    const float* __restrict__ bias,
                                    float* __restrict__ out) {
  const int t = blockIdx.x * 256 + threadIdx.x;
  const int b = t >> 8;
  const int s0 = (t & 255) * 4;
  const size_t rowb = (size_t)b * 4096;
  bf16x4 vl[4];
  #pragma unroll
  for (int l = 0; l < 4; ++l) vl[l] = *(const bf16x4*)(o2 + rowb + l * 1024 + s0);
  #pragma unroll
  for (int si = 0; si < 4; ++si) {
    f32x4 bb = *(const f32x4*)(bias + (size_t)(s0 + si) * 4);
    f32x4 o;
    o[0] = (float)vl[0][si] + bb[0];
    o[1] = (float)vl[1][si] + bb[1];
    o[2] = (float)vl[2][si] + bb[2];
    o[3] = (float)vl[3][si] + bb[3];
    *(f32x4*)(out + rowb + (size_t)(s0 + si) * 4) = o;
  }
}

extern "C" void kernel_launch(void* const* d_in, const int* in_sizes, int n_in,
                              void* d_out, int out_size, void* d_ws, size_t ws_size,
                              hipStream_t stream) {
  const float* x    = (const float*)d_in[0];
  const float* w1   = (const float*)d_in[1];
  const float* w2   = (const float*)d_in[2];
  const float* bias = (const float*)d_in[3];
  float* out = (float*)d_out;

  char* ws = (char*)d_ws;
  const size_t xbBytes    = (size_t)B_DIM * 4096 * 2;   // 134 MB
  const size_t wBytes     = (size_t)8 << 20;            // per w array (bf16)
  const size_t interBytes = (size_t)B_DIM * 4096 * 2;   // 134 MB
  const bool full = ws_size >= xbBytes + 2 * wBytes + interBytes;  // 285 MB

  if (full) {
    bf16_t* xb    = (bf16_t*)(ws);
    bf16_t* w1b   = (bf16_t*)(ws + xbBytes);
    bf16_t* w2b   = (bf16_t*)(ws + xbBytes + wBytes);
    bf16_t* inter = (bf16_t*)(ws + xbBytes + 2 * wBytes);
    bf16_t* o2    = xb;   // xb dead after GEMM1; reuse for o2

    cast_all_kernel<<<36864, 256, 0, stream>>>(x, w1, w2, xb, w1b, w2b);
    monarch_gemm<true, 0><<<4096, 256, 0, stream>>>(nullptr, xb, w1b, inter, nullptr, nullptr);
    monarch_gemm<true, 1><<<4096, 256, 0, stream>>>(nullptr, inter, w2b, o2, nullptr, nullptr);
    permute_bias_kernel<<<16384, 256, 0, stream>>>(o2, bias, out);
  } else {
    bf16_t* w1b   = (bf16_t*)(ws);
    bf16_t* w2b   = (bf16_t*)(ws + wBytes);
    bf16_t* inter = (bf16_t*)(ws + 2 * wBytes);
    cast_w_kernel<<<dim3(2048, 2), 256, 0, stream>>>(w1, w2, w1b, w2b);
    monarch_gemm<false, 0><<<4096, 256, 0, stream>>>(x, nullptr, w1b, inter, nullptr, nullptr);
    monarch_gemm<true, 2><<<4096, 256, 0, stream>>>(nullptr, inter, w2b, nullptr, out, bias);
  }
}

// Round 3
// 516.263 us; speedup vs baseline: 1.2964x; 1.2412x over previous
//
#include <hip/hip_runtime.h>
#include <hip/hip_bf16.h>
#include <stdint.h>

typedef __bf16 bf16_t;
typedef bf16_t bf16x8 __attribute__((ext_vector_type(8)));
typedef bf16_t bf16x4 __attribute__((ext_vector_type(4)));
typedef float  f32x4  __attribute__((ext_vector_type(4)));

#define B_DIM 16384

#define BAR()    __builtin_amdgcn_s_barrier()
#define SCHED0() __builtin_amdgcn_sched_barrier(0)
#define LGKM0()  asm volatile("s_waitcnt lgkmcnt(0)" ::: "memory")
#define VMCNT6() asm volatile("s_waitcnt vmcnt(6)" ::: "memory")
#define VMCNT0() asm volatile("s_waitcnt vmcnt(0)" ::: "memory")

// async global->LDS, 16B per lane; LDS dest is wave-uniform base (+lane*16 by HW)
__device__ __forceinline__ void async_copy16(void* lptr, const void* gptr) {
  __builtin_amdgcn_global_load_lds(
      (const __attribute__((address_space(1))) unsigned int*)gptr,
      (__attribute__((address_space(3))) unsigned int*)lptr, 16, 0, 0);
}

// ---------------- cast x + w1 + w2 fp32 -> bf16 ----------------
__global__ void cast_all_kernel(const float* __restrict__ x, const float* __restrict__ w1,
                                const float* __restrict__ w2, bf16_t* __restrict__ xb,
                                bf16_t* __restrict__ w1b, bf16_t* __restrict__ w2b) {
  size_t c = (size_t)blockIdx.x * 256 + threadIdx.x;  // 8-elem chunk id
  const float* s; bf16_t* d; size_t off;
  if (c < 8388608)      { s = x;  d = xb;  off = c; }            // 16384*4096/8
  else if (c < 8912896) { s = w1; d = w1b; off = c - 8388608; }  // 4*1024*1024/8
  else                  { s = w2; d = w2b; off = c - 8912896; }
  size_t i = off * 8;
  f32x4 a = *(const f32x4*)(s + i);
  f32x4 b = *(const f32x4*)(s + i + 4);
  bf16x8 o;
  o[0]=(bf16_t)a[0]; o[1]=(bf16_t)a[1]; o[2]=(bf16_t)a[2]; o[3]=(bf16_t)a[3];
  o[4]=(bf16_t)b[0]; o[5]=(bf16_t)b[1]; o[6]=(bf16_t)b[2]; o[7]=(bf16_t)b[3];
  *(bf16x8*)(d + i) = o;
}

// ============ 256x256 8-phase GEMM (BK=64, 8 waves, 16x16x32 bf16) ============
// EPI 0: P1-scatter -> inter[b*4096 + l*1024 + r]      (GEMM1)
// EPI 1: contiguous -> o2[b*4096 + zi*1024 + s]        (GEMM2)
// LDS 128 KiB: buf0 A[0,32K) B[32K,64K); buf1 A[64K,96K) B[96K,128K).
// Half-tiles: A0/A1 = rows 0-127/128-255 (16 KB each); same for B.
// Schedule (derived ledger, per iter computing T(t0)=buf0 @P1-4, T(t0+1)=buf1 @P5-8):
//   P1: rd A[M0],B[N0](buf0) + stage B1 of T(t0+1)
//   P2: rd A[M1],B[N1](buf0)
//   P3: stage A0 T(t0+2)
//   P4: stage A1,B0 T(t0+2); vmcnt(6)   <- covers through P1's stage
//   P5: rd A[M0],B[N0](buf1) + stage B1 T(t0+2)
//   P6: rd A[M1],B[N1](buf1)
//   P7: stage A0 T(t0+3)
//   P8: stage A1,B0 T(t0+3); vmcnt(6)   <- covers through P5's stage
// Write-safety: every stage issues >=1 phase after its region's last ds_read,
// with barriers in between. Last iter: stages (except P1) off, P4 uses vmcnt(0).
template<int EPI>
__global__ __launch_bounds__(512, 2)
void monarch_gemm8(const bf16_t* __restrict__ Ab, const bf16_t* __restrict__ Wb,
                   bf16_t* __restrict__ Outb)
{
  __shared__ __align__(16) char smem[131072];
  const int tid  = threadIdx.x;
  const int lane = tid & 63;
  const int wid  = tid >> 6;
  const int wm   = wid >> 2;       // 2 (M) x 4 (N) wave grid; wave tile 128x64
  const int wn   = wid & 3;

  // XCD-chunked swizzle: 1024 blocks, 128 consecutive logicals per XCD
  const int pb = blockIdx.x;
  const int lb = (pb & 7) * 128 + (pb >> 3);
  const int zi = lb >> 8;                  // k (GEMM1) or l (GEMM2)
  const int mt = (lb & 255) >> 2;          // 64 M-tiles
  const int nt = lb & 3;                   // 4 N-tiles

  const size_t brow0 = (size_t)mt * 256;
  const int    ncol0 = nt * 256;

  const bf16_t* Asrc = Ab + brow0 * 4096 + (size_t)zi * 1024;          // stride 4096
  const bf16_t* Bsrc = Wb + ((size_t)zi << 20) + (size_t)ncol0 * 1024; // stride 1024

  // staging source swizzle (T2): linear LDS chunk c' holds source chunk c'^(row&7)
  const int sRow = lane >> 3;
  const int sC   = (lane & 7) ^ sRow;

  // stage half h (0=A0,1=A1,2=B0,3=B1) of K-tile t  (2 gload_lds per wave)
  auto stage = [&](int t, int h) {
    const int ldsBase = (t & 1) * 65536 + (h >> 1) * 32768 + (h & 1) * 16384;
    const bf16_t* src = (h < 2) ? (Asrc + (size_t)(h * 128) * 4096 + t * 64)
                                : (Bsrc + (size_t)((h - 2) * 128) * 1024 + t * 64);
    const size_t strideE = (h < 2) ? 4096 : 1024;
    #pragma unroll
    for (int j = 0; j < 2; ++j) {
      const int row = j * 64 + wid * 8 + sRow;
      async_copy16(smem + ldsBase + j * 8192 + wid * 1024,
                   src + (size_t)row * strideE + sC * 8);
    }
  };

  // ds_read addressing (swizzled): chunk c0 read at linear c0^(lane&7)
  const int cs0 = ((0 + (lane >> 4)) ^ (lane & 7)) * 16;   // kk=0
  const int cs1 = ((4 + (lane >> 4)) ^ (lane & 7)) * 16;   // kk=1
  const int aBase = (wm * 128 + (lane & 15)) * 128;
  const int bBase = 32768 + (wn * 64 + (lane & 15)) * 128;

#define RDA(buf, m, kk) (*(const bf16x8*)(smem + (buf)*65536 + aBase + (m)*2048 + ((kk)?cs1:cs0)))
#define RDB(buf, n, kk) (*(const bf16x8*)(smem + (buf)*65536 + bBase + (n)*2048 + ((kk)?cs1:cs0)))

  f32x4 acc[8][4] = {};
  bf16x8 aM0[4][2], aM1[4][2], bN0[2][2], bN1[2][2];

#define MFMA_QUAD(AR, Aarr, NB, Barr)                                              \
  __builtin_amdgcn_s_setprio(1);                                                   \
  _Pragma("unroll") for (int m = 0; m < 4; ++m)                                    \
  _Pragma("unroll") for (int n = 0; n < 2; ++n)                                    \
  _Pragma("unroll") for (int kk = 0; kk < 2; ++kk)                                 \
    acc[(AR)+m][(NB)+n] = __builtin_amdgcn_mfma_f32_16x16x32_bf16(                 \
        Aarr[m][kk], Barr[n][kk], acc[(AR)+m][(NB)+n], 0, 0, 0);                   \
  __builtin_amdgcn_s_setprio(0);

  // ---- prologue: T0 (4 halves) + T1 (A0,A1,B0); keep T1's 6 loads in flight ----
  stage(0,0); stage(0,1); stage(0,2); stage(0,3);
  stage(1,0); stage(1,1); stage(1,2);
  VMCNT6(); SCHED0(); BAR();

  for (int it2 = 0; it2 < 8; ++it2) {
    const int t0 = it2 * 2;
    const bool notlast = (it2 < 7);
    // ---- P1 ----
    #pragma unroll
    for (int m = 0; m < 4; ++m) { aM0[m][0] = RDA(0,m,0); aM0[m][1] = RDA(0,m,1); }
    #pragma unroll
    for (int n = 0; n < 2; ++n) { bN0[n][0] = RDB(0,n,0); bN0[n][1] = RDB(0,n,1); }
    stage(t0+1, 3);
    SCHED0(); BAR(); LGKM0(); SCHED0();
    MFMA_QUAD(0, aM0, 0, bN0);
    SCHED0(); BAR();
    // ---- P2 ----
    #pragma unroll
    for (int m = 0; m < 4; ++m) { aM1[m][0] = RDA(0,m+4,0); aM1[m][1] = RDA(0,m+4,1); }
    #pragma unroll
    for (int n = 0; n < 2; ++n) { bN1[n][0] = RDB(0,n+2,0); bN1[n][1] = RDB(0,n+2,1); }
    SCHED0(); BAR(); LGKM0(); SCHED0();
    MFMA_QUAD(0, aM0, 2, bN1);
    SCHED0(); BAR();
    // ---- P3 ----
    if (notlast) stage(t0+2, 0);
    SCHED0(); BAR();
    MFMA_QUAD(4, aM1, 2, bN1);
    SCHED0(); BAR();
    // ---- P4 ----
    if (notlast) { stage(t0+2, 1); stage(t0+2, 2); VMCNT6(); }
    else         { VMCNT0(); }
    SCHED0(); BAR();
    MFMA_QUAD(4, aM1, 0, bN0);
    SCHED0(); BAR();
    // ---- P5 ----
    #pragma unroll
    for (int m = 0; m < 4; ++m) { aM0[m][0] = RDA(1,m,0); aM0[m][1] = RDA(1,m,1); }
    #pragma unroll
    for (int n = 0; n < 2; ++n) { bN0[n][0] = RDB(1,n,0); bN0[n][1] = RDB(1,n,1); }
    if (notlast) stage(t0+2, 3);
    SCHED0(); BAR(); LGKM0(); SCHED0();
    MFMA_QUAD(0, aM0, 0, bN0);
    SCHED0(); BAR();
    // ---- P6 ----
    #pragma unroll
    for (int m = 0; m < 4; ++m) { aM1[m][0] = RDA(1,m+4,0); aM1[m][1] = RDA(1,m+4,1); }
    #pragma unroll
    for (int n = 0; n < 2; ++n) { bN1[n][0] = RDB(1,n+2,0); bN1[n][1] = RDB(1,n+2,1); }
    SCHED0(); BAR(); LGKM0(); SCHED0();
    MFMA_QUAD(0, aM0, 2, bN1);
    SCHED0(); BAR();
    // ---- P7 ----
    if (notlast) stage(t0+3, 0);
    SCHED0(); BAR();
    MFMA_QUAD(4, aM1, 2, bN1);
    SCHED0(); BAR();
    // ---- P8 ----
    if (notlast) { stage(t0+3, 1); stage(t0+3, 2); VMCNT6(); }
    SCHED0(); BAR();
    MFMA_QUAD(4, aM1, 0, bN0);
    SCHED0(); BAR();
  }

  // ---- epilogue: two 128-row halves through LDS (reuse; vmcnt drained) ----
  bf16_t* C = (bf16_t*)smem;   // [128][264] padded
  #pragma unroll
  for (int half = 0; half < 2; ++half) {
    BAR();
    if (wm == half) {
      const int rg = lane >> 4, cl = lane & 15;
      #pragma unroll
      for (int m = 0; m < 8; ++m)
        #pragma unroll
        for (int n = 0; n < 4; ++n) {
          const int rl = m * 16 + rg * 4;
          const int col = wn * 64 + n * 16 + cl;
          #pragma unroll
          for (int j = 0; j < 4; ++j)
            C[(rl + j) * 264 + col] = (bf16_t)acc[m][n][j];
        }
    }
    BAR();
    if (EPI == 0) {
      // P1 scatter: col c -> l=c&3, r = zi*256 + nt*64 + (c>>2); 16B runs
      #pragma unroll
      for (int i = 0; i < 8; ++i) {
        const int s = i * 512 + tid;
        const int row = s >> 5, l = (s >> 3) & 3, part = s & 7;
        bf16x8 v;
        #pragma unroll
        for (int u = 0; u < 8; ++u) v[u] = C[row * 264 + l + 4 * (part * 8 + u)];
        *(bf16x8*)&Outb[(brow0 + half * 128 + row) * 4096 +
                        l * 1024 + zi * 256 + nt * 64 + part * 8] = v;
      }
    } else {
      #pragma unroll
      for (int i = 0; i < 8; ++i) {
        const int s = i * 512 + tid;
        const int row = s >> 5, ch = s & 31;
        bf16x8 v = *(const bf16x8*)&C[row * 264 + ch * 8];
        *(bf16x8*)&Outb[(brow0 + half * 128 + row) * 4096 +
                        (size_t)zi * 1024 + ncol0 + ch * 8] = v;
      }
    }
  }
#undef RDA
#undef RDB
#undef MFMA_QUAD
}

// ---------------- P2 + bias: out[b, s*4+l] = o2[b,l,s] + bias ----------------
__global__ void permute_bias_kernel(const bf16_t* __restrict__ o2,
                                    const float* __restrict__ bias,
                                    float* __restrict__ out) {
  const int t = blockIdx.x * 256 + threadIdx.x;
  const int b = t >> 8;
  const int s0 = (t & 255) * 4;
  const size_t rowb = (size_t)b * 4096;
  bf16x4 vl[4];
  #pragma unroll
  for (int l = 0; l < 4; ++l) vl[l] = *(const bf16x4*)(o2 + rowb + l * 1024 + s0);
  #pragma unroll
  for (int si = 0; si < 4; ++si) {
    f32x4 bb = *(const f32x4*)(bias + (size_t)(s0 + si) * 4);
    f32x4 o;
    o[0] = (float)vl[0][si] + bb[0];
    o[1] = (float)vl[1][si] + bb[1];
    o[2] = (float)vl[2][si] + bb[2];
    o[3] = (float)vl[3][si] + bb[3];
    *(f32x4*)(out + rowb + (size_t)(s0 + si) * 4) = o;
  }
}

extern "C" void kernel_launch(void* const* d_in, const int* in_sizes, int n_in,
                              void* d_out, int out_size, void* d_ws, size_t ws_size,
                              hipStream_t stream) {
  const float* x    = (const float*)d_in[0];
  const float* w1   = (const float*)d_in[1];
  const float* w2   = (const float*)d_in[2];
  const float* bias = (const float*)d_in[3];
  float* out = (float*)d_out;

  char* ws = (char*)d_ws;
  const size_t xbBytes    = (size_t)B_DIM * 4096 * 2;   // 134 MB
  const size_t wBytes     = (size_t)8 << 20;            // per w array (bf16)
  bf16_t* xb    = (bf16_t*)(ws);
  bf16_t* w1b   = (bf16_t*)(ws + xbBytes);
  bf16_t* w2b   = (bf16_t*)(ws + xbBytes + wBytes);
  bf16_t* inter = (bf16_t*)(ws + xbBytes + 2 * wBytes);
  bf16_t* o2    = xb;   // xb dead after GEMM1; reuse for o2

  cast_all_kernel<<<36864, 256, 0, stream>>>(x, w1, w2, xb, w1b, w2b);
  monarch_gemm8<0><<<1024, 512, 0, stream>>>(xb, w1b, inter);
  monarch_gemm8<1><<<1024, 512, 0, stream>>>(inter, w2b, o2);
  permute_bias_kernel<<<16384, 256, 0, stream>>>(o2, bias, out);
}

// Round 4
// 491.565 us; speedup vs baseline: 1.3615x; 1.0502x over previous
//
#include <hip/hip_runtime.h>
#include <hip/hip_bf16.h>
#include <stdint.h>

typedef __bf16 bf16_t;
typedef bf16_t bf16x8 __attribute__((ext_vector_type(8)));
typedef bf16_t bf16x4 __attribute__((ext_vector_type(4)));
typedef float  f32x4  __attribute__((ext_vector_type(4)));

#define B_DIM 16384

// memory-fenced barrier: compiler may not move LDS/global ops across it
#define BARM()   asm volatile("s_barrier" ::: "memory")
#define SCHED0() __builtin_amdgcn_sched_barrier(0)
#define LGKM0()  asm volatile("s_waitcnt lgkmcnt(0)" ::: "memory")
#define VMCNT6() asm volatile("s_waitcnt vmcnt(6)" ::: "memory")
#define VMCNT0() asm volatile("s_waitcnt vmcnt(0)" ::: "memory")

// async global->LDS, 16B per lane; LDS dest is wave-uniform base (+lane*16 by HW)
__device__ __forceinline__ void async_copy16(void* lptr, const void* gptr) {
  __builtin_amdgcn_global_load_lds(
      (const __attribute__((address_space(1))) unsigned int*)gptr,
      (__attribute__((address_space(3))) unsigned int*)lptr, 16, 0, 0);
}

// ---------------- cast x + w1 + w2 fp32 -> bf16 ----------------
__global__ void cast_all_kernel(const float* __restrict__ x, const float* __restrict__ w1,
                                const float* __restrict__ w2, bf16_t* __restrict__ xb,
                                bf16_t* __restrict__ w1b, bf16_t* __restrict__ w2b) {
  size_t c = (size_t)blockIdx.x * 256 + threadIdx.x;  // 8-elem chunk id
  const float* s; bf16_t* d; size_t off;
  if (c < 8388608)      { s = x;  d = xb;  off = c; }            // 16384*4096/8
  else if (c < 8912896) { s = w1; d = w1b; off = c - 8388608; }  // 4*1024*1024/8
  else                  { s = w2; d = w2b; off = c - 8912896; }
  size_t i = off * 8;
  f32x4 a = *(const f32x4*)(s + i);
  f32x4 b = *(const f32x4*)(s + i + 4);
  bf16x8 o;
  o[0]=(bf16_t)a[0]; o[1]=(bf16_t)a[1]; o[2]=(bf16_t)a[2]; o[3]=(bf16_t)a[3];
  o[4]=(bf16_t)b[0]; o[5]=(bf16_t)b[1]; o[6]=(bf16_t)b[2]; o[7]=(bf16_t)b[3];
  *(bf16x8*)(d + i) = o;
}

// ============ 256x256 8-phase GEMM (BK=64, 8 waves, 16x16x32 bf16) ============
// EPI 0: P1-scatter -> inter[b*4096 + l*1024 + r]      (GEMM1)
// EPI 1: contiguous -> o2[b*4096 + zi*1024 + s]        (GEMM2)
// LDS 128 KiB: buf0 A[0,32K) B[32K,64K); buf1 A[64K,96K) B[96K,128K).
// Quad order (M0N0)(M1N0)(M0N1)(M1N1): phase reads 8/8/4/4 (bN0 via lookahead
// in the preceding vmcnt-publishing phase). Stage slots unchanged from R3
// (ledger verified: every stage's target has last-ds_read >= 2 phases earlier;
// vmcnt(6) at P4/P8 completes exactly the tile needed by the next buf reads).
template<int EPI>
__global__ __launch_bounds__(512, 2)
void monarch_gemm8(const bf16_t* __restrict__ Ab, const bf16_t* __restrict__ Wb,
                   bf16_t* __restrict__ Outb)
{
  __shared__ __align__(16) char smem[131072];
  const int tid  = threadIdx.x;
  const int lane = tid & 63;
  const int wid  = tid >> 6;
  const int wm   = wid >> 2;       // 2 (M) x 4 (N) wave grid; wave tile 128x64
  const int wn   = wid & 3;

  // XCD-chunked swizzle: 1024 blocks, 128 consecutive logicals per XCD
  const int pb = blockIdx.x;
  const int lb = (pb & 7) * 128 + (pb >> 3);
  const int zi = lb >> 8;                  // k (GEMM1) or l (GEMM2)
  const int mt = (lb & 255) >> 2;          // 64 M-tiles
  const int nt = lb & 3;                   // 4 N-tiles

  const size_t brow0 = (size_t)mt * 256;
  const int    ncol0 = nt * 256;

  const bf16_t* Asrc = Ab + brow0 * 4096 + (size_t)zi * 1024;          // stride 4096
  const bf16_t* Bsrc = Wb + ((size_t)zi << 20) + (size_t)ncol0 * 1024; // stride 1024

  // staging source swizzle (T2): linear LDS chunk c' holds source chunk c'^(row&7)
  const int sRow = lane >> 3;
  const int sC   = (lane & 7) ^ sRow;

  // stage half h (0=A0,1=A1,2=B0,3=B1) of K-tile t  (2 gload_lds per wave)
  auto stage = [&](int t, int h) {
    const int ldsBase = (t & 1) * 65536 + (h >> 1) * 32768 + (h & 1) * 16384;
    const bf16_t* src = (h < 2) ? (Asrc + (size_t)(h * 128) * 4096 + t * 64)
                                : (Bsrc + (size_t)((h - 2) * 128) * 1024 + t * 64);
    const size_t strideE = (h < 2) ? 4096 : 1024;
    #pragma unroll
    for (int j = 0; j < 2; ++j) {
      const int row = j * 64 + wid * 8 + sRow;
      async_copy16(smem + ldsBase + j * 8192 + wid * 1024,
                   src + (size_t)row * strideE + sC * 8);
    }
  };

  // ds_read addressing (swizzled): chunk c0 read at linear c0^(lane&7)
  const int cs0 = ((0 + (lane >> 4)) ^ (lane & 7)) * 16;   // kk=0
  const int cs1 = ((4 + (lane >> 4)) ^ (lane & 7)) * 16;   // kk=1
  const int aBase = (wm * 128 + (lane & 15)) * 128;
  const int bBase = 32768 + (wn * 64 + (lane & 15)) * 128;

#define RDA(buf, m, kk) (*(const bf16x8*)(smem + (buf)*65536 + aBase + (m)*2048 + ((kk)?cs1:cs0)))
#define RDB(buf, n, kk) (*(const bf16x8*)(smem + (buf)*65536 + bBase + (n)*2048 + ((kk)?cs1:cs0)))

  f32x4 acc[8][4] = {};
  bf16x8 aM0[4][2], aM1[4][2], bN0[2][2], bN1[2][2];

#define MFMA_QUAD(AR, Aarr, NB, Barr)                                              \
  __builtin_amdgcn_s_setprio(1);                                                   \
  _Pragma("unroll") for (int m = 0; m < 4; ++m)                                    \
  _Pragma("unroll") for (int n = 0; n < 2; ++n)                                    \
  _Pragma("unroll") for (int kk = 0; kk < 2; ++kk)                                 \
    acc[(AR)+m][(NB)+n] = __builtin_amdgcn_mfma_f32_16x16x32_bf16(                 \
        Aarr[m][kk], Barr[n][kk], acc[(AR)+m][(NB)+n], 0, 0, 0);                   \
  __builtin_amdgcn_s_setprio(0);

#define LD_A0(buf) _Pragma("unroll") for (int m = 0; m < 4; ++m) { \
    aM0[m][0] = RDA(buf,m,0); aM0[m][1] = RDA(buf,m,1); }
#define LD_A1(buf) _Pragma("unroll") for (int m = 0; m < 4; ++m) { \
    aM1[m][0] = RDA(buf,m+4,0); aM1[m][1] = RDA(buf,m+4,1); }
#define LD_B0(buf) _Pragma("unroll") for (int n = 0; n < 2; ++n) { \
    bN0[n][0] = RDB(buf,n,0); bN0[n][1] = RDB(buf,n,1); }
#define LD_B1(buf) _Pragma("unroll") for (int n = 0; n < 2; ++n) { \
    bN1[n][0] = RDB(buf,n+2,0); bN1[n][1] = RDB(buf,n+2,1); }

  // ---- prologue: T0 (4 halves) + T1 (A0,A1,B0); keep T1's 6 loads in flight ----
  stage(0,0); stage(0,1); stage(0,2); stage(0,3);
  stage(1,0); stage(1,1); stage(1,2);
  VMCNT6(); BARM();
  LD_B0(0);                       // bN0 lookahead for iter0 P1 (T0 published)

  for (int it2 = 0; it2 < 8; ++it2) {
    const int t0 = it2 * 2;
    const bool notlast = (it2 < 7);
    // ---- P1: read aM0(buf0); MFMA M0xN0 ----
    LD_A0(0);
    stage(t0+1, 3);
    BARM(); LGKM0(); SCHED0();
    MFMA_QUAD(0, aM0, 0, bN0);
    BARM();
    // ---- P2: read aM1(buf0); MFMA M1xN0 ----
    LD_A1(0);
    BARM(); LGKM0(); SCHED0();
    MFMA_QUAD(4, aM1, 0, bN0);
    BARM();
    // ---- P3: read bN1(buf0); MFMA M0xN1 ----
    LD_B1(0);
    if (notlast) stage(t0+2, 0);
    BARM(); LGKM0(); SCHED0();
    MFMA_QUAD(0, aM0, 2, bN1);
    BARM();
    // ---- P4: stages + vmcnt publish buf1; lookahead bN0(buf1); MFMA M1xN1 ----
    if (notlast) { stage(t0+2, 1); stage(t0+2, 2); VMCNT6(); }
    else         { VMCNT0(); }
    BARM();
    LD_B0(1);
    MFMA_QUAD(4, aM1, 2, bN1);
    BARM();
    // ---- P5: read aM0(buf1); MFMA M0xN0 ----
    LD_A0(1);
    if (notlast) stage(t0+2, 3);
    BARM(); LGKM0(); SCHED0();
    MFMA_QUAD(0, aM0, 0, bN0);
    BARM();
    // ---- P6: read aM1(buf1); MFMA M1xN0 ----
    LD_A1(1);
    BARM(); LGKM0(); SCHED0();
    MFMA_QUAD(4, aM1, 0, bN0);
    BARM();
    // ---- P7: read bN1(buf1); MFMA M0xN1 ----
    LD_B1(1);
    if (notlast) stage(t0+3, 0);
    BARM(); LGKM0(); SCHED0();
    MFMA_QUAD(0, aM0, 2, bN1);
    BARM();
    // ---- P8: stages + vmcnt publish buf0(next); lookahead bN0(buf0); MFMA M1xN1 ----
    if (notlast) { stage(t0+3, 1); stage(t0+3, 2); VMCNT6(); }
    BARM();
    if (notlast) { LD_B0(0); }
    MFMA_QUAD(4, aM1, 2, bN1);
    BARM();
  }

  // ---- epilogue: two 128-row halves through LDS (reuse; vmcnt drained) ----
  bf16_t* C = (bf16_t*)smem;   // [128][264] padded
  #pragma unroll
  for (int half = 0; half < 2; ++half) {
    BARM();
    if (wm == half) {
      const int rg = lane >> 4, cl = lane & 15;
      #pragma unroll
      for (int m = 0; m < 8; ++m)
        #pragma unroll
        for (int n = 0; n < 4; ++n) {
          const int rl = m * 16 + rg * 4;
          const int col = wn * 64 + n * 16 + cl;
          #pragma unroll
          for (int j = 0; j < 4; ++j)
            C[(rl + j) * 264 + col] = (bf16_t)acc[m][n][j];
        }
    }
    BARM();
    if (EPI == 0) {
      // P1 scatter: col c -> l=c&3, r = zi*256 + nt*64 + (c>>2); 16B runs
      #pragma unroll
      for (int i = 0; i < 8; ++i) {
        const int s = i * 512 + tid;
        const int row = s >> 5, l = (s >> 3) & 3, part = s & 7;
        bf16x8 v;
        #pragma unroll
        for (int u = 0; u < 8; ++u) v[u] = C[row * 264 + l + 4 * (part * 8 + u)];
        *(bf16x8*)&Outb[(brow0 + half * 128 + row) * 4096 +
                        l * 1024 + zi * 256 + nt * 64 + part * 8] = v;
      }
    } else {
      #pragma unroll
      for (int i = 0; i < 8; ++i) {
        const int s = i * 512 + tid;
        const int row = s >> 5, ch = s & 31;
        bf16x8 v = *(const bf16x8*)&C[row * 264 + ch * 8];
        *(bf16x8*)&Outb[(brow0 + half * 128 + row) * 4096 +
                        (size_t)zi * 1024 + ncol0 + ch * 8] = v;
      }
    }
  }
#undef RDA
#undef RDB
#undef MFMA_QUAD
#undef LD_A0
#undef LD_A1
#undef LD_B0
#undef LD_B1
}

// ---------------- P2 + bias: out[b, s*4+l] = o2[b,l,s] + bias ----------------
__global__ void permute_bias_kernel(const bf16_t* __restrict__ o2,
                                    const float* __restrict__ bias,
                                    float* __restrict__ out) {
  const int t = blockIdx.x * 256 + threadIdx.x;
  const int b = t >> 8;
  const int s0 = (t & 255) * 4;
  const size_t rowb = (size_t)b * 4096;
  bf16x4 vl[4];
  #pragma unroll
  for (int l = 0; l < 4; ++l) vl[l] = *(const bf16x4*)(o2 + rowb + l * 1024 + s0);
  #pragma unroll
  for (int si = 0; si < 4; ++si) {
    f32x4 bb = *(const f32x4*)(bias + (size_t)(s0 + si) * 4);
    f32x4 o;
    o[0] = (float)vl[0][si] + bb[0];
    o[1] = (float)vl[1][si] + bb[1];
    o[2] = (float)vl[2][si] + bb[2];
    o[3] = (float)vl[3][si] + bb[3];
    *(f32x4*)(out + rowb + (size_t)(s0 + si) * 4) = o;
  }
}

extern "C" void kernel_launch(void* const* d_in, const int* in_sizes, int n_in,
                              void* d_out, int out_size, void* d_ws, size_t ws_size,
                              hipStream_t stream) {
  const float* x    = (const float*)d_in[0];
  const float* w1   = (const float*)d_in[1];
  const float* w2   = (const float*)d_in[2];
  const float* bias = (const float*)d_in[3];
  float* out = (float*)d_out;

  char* ws = (char*)d_ws;
  const size_t xbBytes    = (size_t)B_DIM * 4096 * 2;   // 134 MB
  const size_t wBytes     = (size_t)8 << 20;            // per w array (bf16)
  bf16_t* xb    = (bf16_t*)(ws);
  bf16_t* w1b   = (bf16_t*)(ws + xbBytes);
  bf16_t* w2b   = (bf16_t*)(ws + xbBytes + wBytes);
  bf16_t* inter = (bf16_t*)(ws + xbBytes + 2 * wBytes);
  bf16_t* o2    = xb;   // xb dead after GEMM1; reuse for o2

  cast_all_kernel<<<36864, 256, 0, stream>>>(x, w1, w2, xb, w1b, w2b);
  monarch_gemm8<0><<<1024, 512, 0, stream>>>(xb, w1b, inter);
  monarch_gemm8<1><<<1024, 512, 0, stream>>>(inter, w2b, o2);
  permute_bias_kernel<<<16384, 256, 0, stream>>>(o2, bias, out);
}